// Round 7
// baseline (100.641 us; speedup 1.0000x reference)
//
#include <hip/hip_runtime.h>
#include <hip/hip_bf16.h>

namespace {

constexpr int kBatch  = 524288;
constexpr int kD      = 16;
constexpr int kOffset = 38167;   // TOTAL - N_GENRES
constexpr int kNG     = 18;

// s_w byte-offset layout (identical image in d_ws and LDS; swizzle pre-baked).
constexpr int W1B0   = 0;        // W1^T swz [64][64] bf16 (k 0..47 valid, 48..63 zero)
constexpr int W2B0   = 8192;     // W2^T swz [32][64]
constexpr int W3B0   = 12288;    // W3^T swz [16][32]
constexpr int GB0    = 13312;    // genre B-frag table [64 rows=(4c+g)][8] bf16
constexpr int WBYTES = 14336;    // = 896 uint4

typedef __attribute__((ext_vector_type(8))) short short8;   // MFMA A/B frag
typedef __attribute__((ext_vector_type(4))) float f32x4;    // MFMA C/D frag
typedef __attribute__((ext_vector_type(2))) float f32x2;

__device__ __forceinline__ unsigned short f2bf(float f) {
    return __builtin_bit_cast(unsigned short, __float2bfloat16(f));
}
__device__ __forceinline__ unsigned pk2(float a, float b) {
    return (unsigned)f2bf(a) | ((unsigned)f2bf(b) << 16);
}
__device__ __forceinline__ float bf2f(unsigned short s) {
    union { unsigned u; float f; } v; v.u = ((unsigned)s) << 16;
    return v.f;
}
// Swizzled act pointer: [64 rows][64 bf16] 128B rows; 16B-granule index XOR'd
// with (row&7). Valid for any byteCol<128 (XOR touches bits 4..6 only).
__device__ __forceinline__ unsigned short* AP(unsigned short* b, int row, int col) {
    return (unsigned short*)((char*)b + row * 128 + ((col * 2) ^ ((row & 7) << 4)));
}
__device__ __forceinline__ const unsigned short* APc(const unsigned short* b, int row, int col) {
    return (const unsigned short*)((const char*)b + row * 128 + ((col * 2) ^ ((row & 7) << 4)));
}

// ---------------- prep: build swizzled bf16 weight image in d_ws ----------------
__global__ void prep_weights(const float* __restrict__ emb,
                             const float* __restrict__ W1,
                             const float* __restrict__ W2,
                             const float* __restrict__ W3,
                             unsigned short* __restrict__ wimg)
{
    const int t = (int)threadIdx.x;             // 256 threads, 1 block
    for (int i = t; i < WBYTES / 2; i += 256) wimg[i] = 0;
    __syncthreads();
    for (int i = t; i < 48 * 64; i += 256) {    // W1^T, swizzled rows
        int k = i >> 6, n = i & 63;
        int byte = W1B0 + n * 128 + ((k * 2) ^ ((n & 7) << 4));
        wimg[byte >> 1] = f2bf(W1[k * 64 + n]);
    }
    for (int i = t; i < 64 * 32; i += 256) {    // W2^T
        int k = i >> 5, n = i & 31;
        int byte = W2B0 + n * 128 + ((k * 2) ^ ((n & 7) << 4));
        wimg[byte >> 1] = f2bf(W2[k * 32 + n]);
    }
    for (int i = t; i < 32 * 16; i += 256) {    // W3^T (64B rows, XOR with n&3)
        int k = i >> 4, n = i & 15;
        int byte = W3B0 + n * 64 + ((k * 2) ^ ((n & 3) << 4));
        wimg[byte >> 1] = f2bf(W3[k * 16 + n]);
    }
    for (int i = t; i < 512; i += 256) {        // genre B-frag: row 4c+g holds G[8g+j][c]
        int c = i >> 5, r = i & 31, g = r >> 3, j = r & 7;
        int kg = 8 * g + j;
        wimg[(GB0 >> 1) + (4 * c + g) * 8 + j] =
            (kg < kNG) ? f2bf(emb[(size_t)(kOffset + kg) * kD + c]) : (unsigned short)0;
    }
}

// ---------------- one 64-sample tile: stage -> bag -> FM -> MLP -> store ----------------
__device__ __forceinline__ void tile_compute(
    unsigned short* __restrict__ aw, const unsigned short* __restrict__ s_w,
    int lane, int c, int g,
    const unsigned (&mw)[9], const float (&h)[32], float lin,
    const float (&b1v)[4], const float (&b2v)[2], float b3v,
    const float* __restrict__ W4, float* __restrict__ out, int i)
{
    const f32x4 z4 = {0.f, 0.f, 0.f, 0.f};
    const f32x2 zz = {0.f, 0.f};

    // ---- stage mask (bf16 0/1) cols 0..31; zeros cols 48..63 (L1 K-pad) ----
    {
        uint4 v0; v0.x = mw[0]; v0.y = mw[1]; v0.z = mw[2]; v0.w = mw[3];
        uint4 v1; v1.x = mw[4]; v1.y = mw[5]; v1.z = mw[6]; v1.w = mw[7];
        uint4 v2; v2.x = mw[8]; v2.y = 0u;    v2.z = 0u;    v2.w = 0u;
        uint4 vz; vz.x = vz.y = vz.z = vz.w = 0u;
        *reinterpret_cast<uint4*>(AP(aw, lane,  0)) = v0;
        *reinterpret_cast<uint4*>(AP(aw, lane,  8)) = v1;
        *reinterpret_cast<uint4*>(AP(aw, lane, 16)) = v2;
        *reinterpret_cast<uint4*>(AP(aw, lane, 24)) = vz;
        *reinterpret_cast<uint4*>(AP(aw, lane, 48)) = vz;
        *reinterpret_cast<uint4*>(AP(aw, lane, 56)) = vz;
    }

    // ---- embedding-bag via MFMA: e_mh = m @ G  -> act cols 32..47 ----
    {
        const short8 bfrag = *reinterpret_cast<const short8*>(s_w + (GB0 >> 1) + (4 * c + g) * 8);
        short8 af[4];
        #pragma unroll
        for (int mt = 0; mt < 4; ++mt)
            af[mt] = *reinterpret_cast<const short8*>(APc(aw, 16 * mt + c, 8 * g));
        f32x4 accb[4];
        #pragma unroll
        for (int mt = 0; mt < 4; ++mt)
            accb[mt] = __builtin_amdgcn_mfma_f32_16x16x32_bf16(af[mt], bfrag, z4, 0, 0, 0);
        #pragma unroll
        for (int mt = 0; mt < 4; ++mt)
            #pragma unroll
            for (int r = 0; r < 4; ++r)
                *AP(aw, 16 * mt + 4 * g + r, 32 + c) = f2bf(accb[mt][r]);
    }

    // ---- pack e_user|e_item -> act cols 0..31 (after bag A-reads; same-wave DS order) ----
    {
        #pragma unroll
        for (int q = 0; q < 4; ++q) {
            uint4 d;
            d.x = pk2(h[8*q+0], h[8*q+1]);
            d.y = pk2(h[8*q+2], h[8*q+3]);
            d.z = pk2(h[8*q+4], h[8*q+5]);
            d.w = pk2(h[8*q+6], h[8*q+7]);
            *reinterpret_cast<uint4*>(AP(aw, lane, 8 * q)) = d;
        }
    }

    // ---- read back e_mh for FM ----
    float fm = 0.f;
    {
        const uint4 p0 = *reinterpret_cast<const uint4*>(APc(aw, lane, 32));
        const uint4 p1 = *reinterpret_cast<const uint4*>(APc(aw, lane, 40));
        const unsigned pp[8] = {p0.x, p0.y, p0.z, p0.w, p1.x, p1.y, p1.z, p1.w};
        float em[16];
        #pragma unroll
        for (int j = 0; j < 8; ++j) {
            em[2*j+0] = bf2f((unsigned short)(pp[j] & 0xFFFFu));
            em[2*j+1] = bf2f((unsigned short)(pp[j] >> 16));
        }
        #pragma unroll
        for (int d = 0; d < kD; ++d) fm = fmaf(h[d], h[16 + d], fm);
        #pragma unroll
        for (int d = 0; d < kD; ++d) fm = fmaf(h[d] + h[16 + d], em[d], fm);
    }

    // ================= L1: act[64x64] @ W1 (K=48 padded to 64), mt-PAIRS =================
    // Pair p handles m-tiles {2p, 2p+1}: all A-reads of the pair (old act rows
    // 32p..32p+31) precede the pair's epilogue writes (h1 rows 32p..32p+31);
    // pair 1's reads (rows 32..63) are disjoint from pair 0's writes (rows 0..31).
    #pragma unroll
    for (int p = 0; p < 2; ++p) {
        short8 af[2][2];     // [mtl][kt]
        #pragma unroll
        for (int mtl = 0; mtl < 2; ++mtl)
            #pragma unroll
            for (int kt = 0; kt < 2; ++kt)
                af[mtl][kt] = *reinterpret_cast<const short8*>(
                    APc(aw, 16*(2*p + mtl) + c, 32*kt + 8*g));
        f32x4 a1[2][4];
        #pragma unroll
        for (int mtl = 0; mtl < 2; ++mtl)
            #pragma unroll
            for (int nt = 0; nt < 4; ++nt) a1[mtl][nt] = z4;
        #pragma unroll
        for (int kt = 0; kt < 2; ++kt) {
            short8 bfr[4];
            #pragma unroll
            for (int nt = 0; nt < 4; ++nt)
                bfr[nt] = *reinterpret_cast<const short8*>(
                    (const char*)s_w + W1B0 + (16*nt + c) * 128 + ((64*kt + 16*g) ^ ((c & 7) << 4)));
            #pragma unroll
            for (int mtl = 0; mtl < 2; ++mtl)
                #pragma unroll
                for (int nt = 0; nt < 4; ++nt)
                    a1[mtl][nt] = __builtin_amdgcn_mfma_f32_16x16x32_bf16(af[mtl][kt], bfr[nt], a1[mtl][nt], 0, 0, 0);
        }
        #pragma unroll
        for (int mtl = 0; mtl < 2; ++mtl)
            #pragma unroll
            for (int nt = 0; nt < 4; ++nt) {
                f32x2 p0 = {a1[mtl][nt][0], a1[mtl][nt][1]};
                f32x2 p1 = {a1[mtl][nt][2], a1[mtl][nt][3]};
                const f32x2 bb = {b1v[nt], b1v[nt]};
                p0 += bb; p1 += bb;
                p0 = __builtin_elementwise_max(p0, zz);
                p1 = __builtin_elementwise_max(p1, zz);
                const int mr = 16*(2*p + mtl) + 4*g;
                *AP(aw, mr + 0, 16*nt + c) = f2bf(p0[0]);
                *AP(aw, mr + 1, 16*nt + c) = f2bf(p0[1]);
                *AP(aw, mr + 2, 16*nt + c) = f2bf(p1[0]);
                *AP(aw, mr + 3, 16*nt + c) = f2bf(p1[1]);
            }
    }

    // ================= L2: h1[64x64] @ W2[64x32] =================
    f32x4 acc2[4][2];
    #pragma unroll
    for (int mt = 0; mt < 4; ++mt)
        #pragma unroll
        for (int nt = 0; nt < 2; ++nt) acc2[mt][nt] = z4;
    #pragma unroll
    for (int kt = 0; kt < 2; ++kt) {
        short8 af[4], bfr[2];
        #pragma unroll
        for (int mt = 0; mt < 4; ++mt)
            af[mt] = *reinterpret_cast<const short8*>(APc(aw, 16*mt + c, 32*kt + 8*g));
        #pragma unroll
        for (int nt = 0; nt < 2; ++nt)
            bfr[nt] = *reinterpret_cast<const short8*>(
                (const char*)s_w + W2B0 + (16*nt + c) * 128 + ((64*kt + 16*g) ^ ((c & 7) << 4)));
        #pragma unroll
        for (int mt = 0; mt < 4; ++mt)
            #pragma unroll
            for (int nt = 0; nt < 2; ++nt)
                acc2[mt][nt] = __builtin_amdgcn_mfma_f32_16x16x32_bf16(af[mt], bfr[nt], acc2[mt][nt], 0, 0, 0);
    }
    #pragma unroll
    for (int mt = 0; mt < 4; ++mt)
        #pragma unroll
        for (int nt = 0; nt < 2; ++nt) {
            f32x2 p0 = {acc2[mt][nt][0], acc2[mt][nt][1]};
            f32x2 p1 = {acc2[mt][nt][2], acc2[mt][nt][3]};
            const f32x2 bb = {b2v[nt], b2v[nt]};
            p0 += bb; p1 += bb;
            p0 = __builtin_elementwise_max(p0, zz);
            p1 = __builtin_elementwise_max(p1, zz);
            *AP(aw, 16*mt + 4*g + 0, 16*nt + c) = f2bf(p0[0]);
            *AP(aw, 16*mt + 4*g + 1, 16*nt + c) = f2bf(p0[1]);
            *AP(aw, 16*mt + 4*g + 2, 16*nt + c) = f2bf(p1[0]);
            *AP(aw, 16*mt + 4*g + 3, 16*nt + c) = f2bf(p1[1]);
        }

    // ================= L3: h2[64x32] @ W3[32x16] =================
    f32x4 acc3[4];
    #pragma unroll
    for (int mt = 0; mt < 4; ++mt) acc3[mt] = z4;
    {
        const short8 bfr = *reinterpret_cast<const short8*>(
            (const char*)s_w + W3B0 + c * 64 + ((16*g) ^ ((c & 3) << 4)));
        short8 af[4];
        #pragma unroll
        for (int mt = 0; mt < 4; ++mt)
            af[mt] = *reinterpret_cast<const short8*>(APc(aw, 16*mt + c, 8*g));
        #pragma unroll
        for (int mt = 0; mt < 4; ++mt)
            acc3[mt] = __builtin_amdgcn_mfma_f32_16x16x32_bf16(af[mt], bfr, acc3[mt], 0, 0, 0);
    }
    #pragma unroll
    for (int mt = 0; mt < 4; ++mt) {
        f32x2 p0 = {acc3[mt][0], acc3[mt][1]};
        f32x2 p1 = {acc3[mt][2], acc3[mt][3]};
        const f32x2 bb = {b3v, b3v};
        p0 += bb; p1 += bb;
        p0 = __builtin_elementwise_max(p0, zz);
        p1 = __builtin_elementwise_max(p1, zz);
        *AP(aw, 16*mt + 4*g + 0, c) = f2bf(p0[0]);
        *AP(aw, 16*mt + 4*g + 1, c) = f2bf(p0[1]);
        *AP(aw, 16*mt + 4*g + 2, c) = f2bf(p1[0]);
        *AP(aw, 16*mt + 4*g + 3, c) = f2bf(p1[1]);
    }

    // ================= L4 (16 -> 1) + combine + sigmoid =================
    float mlp = 0.f;
    {
        const uint4 p0 = *reinterpret_cast<const uint4*>(APc(aw, lane, 0));
        const uint4 p1 = *reinterpret_cast<const uint4*>(APc(aw, lane, 8));
        const unsigned pp[8] = {p0.x, p0.y, p0.z, p0.w, p1.x, p1.y, p1.z, p1.w};
        #pragma unroll
        for (int j = 0; j < 8; ++j) {
            mlp = fmaf(bf2f((unsigned short)(pp[j] & 0xFFFFu)), W4[2*j],     mlp);
            mlp = fmaf(bf2f((unsigned short)(pp[j] >> 16)),     W4[2*j + 1], mlp);
        }
    }

    const float x = lin + fm + mlp;
    out[i] = 1.0f / (1.0f + __expf(-x));
}

// ---------------- main fused kernel: 256 thr, 3 blocks/CU, 2 tiles/wave ----------------
__global__ __launch_bounds__(256, 3) void deepfm_fwd(
    const int*   __restrict__ x_onehot,
    const int*   __restrict__ multi_hot,
    const float* __restrict__ emb,
    const float* __restrict__ fc,
    const unsigned short* __restrict__ wimg,
    const float* __restrict__ b1,
    const float* __restrict__ b2,
    const float* __restrict__ b3,
    const float* __restrict__ W4,
    const float* __restrict__ b4,
    const float* __restrict__ bias,
    float*       __restrict__ out)
{
    __shared__ alignas(16) unsigned short s_w[WBYTES / 2];  // 14336 B
    __shared__ alignas(16) unsigned short s_act[4 * 4096];  // 32768 B (4 waves x 8KB); total 47104 B

    const int t = (int)threadIdx.x;

    // ---- stage weight image global->LDS (896 uint4 over 256 threads) ----
    {
        const uint4* src = reinterpret_cast<const uint4*>(wimg);
        uint4*       dst = reinterpret_cast<uint4*>(s_w);
        #pragma unroll
        for (int q = 0; q < 4; ++q) {
            const int idx = t + 256 * q;
            if (idx < WBYTES / 16) dst[idx] = src[idx];
        }
    }

    const int lane = t & 63;
    const int w    = t >> 6;
    const int c    = lane & 15, g = lane >> 4;
    unsigned short* __restrict__ aw = s_act + w * 4096;

    const int i0 = (int)blockIdx.x * 512 + t;
    const int i1 = i0 + 256;

    // ================= tile 0 front-end =================
    int2 mh0[9];
    {
        const int2* mh2 = reinterpret_cast<const int2*>(multi_hot + (size_t)kNG * i0);
        #pragma unroll
        for (int q = 0; q < 9; ++q) mh0[q] = mh2[q];
    }
    const int2 ids0 = *reinterpret_cast<const int2*>(x_onehot + 2 * (size_t)i0);

    float h0[32];
    {
        const float4* eu = reinterpret_cast<const float4*>(emb + (size_t)ids0.x * kD);
        #pragma unroll
        for (int q = 0; q < 4; ++q) {
            const float4 a = eu[q];
            h0[4*q+0] = a.x; h0[4*q+1] = a.y; h0[4*q+2] = a.z; h0[4*q+3] = a.w;
        }
        const float4* ei = reinterpret_cast<const float4*>(emb + (size_t)ids0.y * kD);
        #pragma unroll
        for (int q = 0; q < 4; ++q) {
            const float4 a = ei[q];
            h0[16+4*q+0] = a.x; h0[16+4*q+1] = a.y; h0[16+4*q+2] = a.z; h0[16+4*q+3] = a.w;
        }
    }

    // per-lane column biases (tile-independent, loaded once)
    float b1v[4];
    #pragma unroll
    for (int nt = 0; nt < 4; ++nt) b1v[nt] = b1[16 * nt + c];
    float b2v[2]; b2v[0] = b2[c]; b2v[1] = b2[16 + c];
    const float b3v = b3[c];
    const float linbase = bias[0] + b4[0];

    float lin0 = linbase + fc[ids0.x] + fc[ids0.y];
    unsigned mw0[9];
    #pragma unroll
    for (int q = 0; q < 9; ++q) {
        lin0 += mh0[q].x ? fc[kOffset + 2 * q]     : 0.f;
        lin0 += mh0[q].y ? fc[kOffset + 2 * q + 1] : 0.f;
        mw0[q] = (mh0[q].x ? 0x3F80u : 0u) | (mh0[q].y ? 0x3F800000u : 0u);
    }

    __syncthreads();   // weight image ready

    // ================= tile 1 front-end (prefetch: lands under tile 0 compute) ======
    int2 mh1[9];
    {
        const int2* mh2 = reinterpret_cast<const int2*>(multi_hot + (size_t)kNG * i1);
        #pragma unroll
        for (int q = 0; q < 9; ++q) mh1[q] = mh2[q];
    }
    const int2 ids1 = *reinterpret_cast<const int2*>(x_onehot + 2 * (size_t)i1);

    float h1[32];
    {
        const float4* eu = reinterpret_cast<const float4*>(emb + (size_t)ids1.x * kD);
        #pragma unroll
        for (int q = 0; q < 4; ++q) {
            const float4 a = eu[q];
            h1[4*q+0] = a.x; h1[4*q+1] = a.y; h1[4*q+2] = a.z; h1[4*q+3] = a.w;
        }
        const float4* ei = reinterpret_cast<const float4*>(emb + (size_t)ids1.y * kD);
        #pragma unroll
        for (int q = 0; q < 4; ++q) {
            const float4 a = ei[q];
            h1[16+4*q+0] = a.x; h1[16+4*q+1] = a.y; h1[16+4*q+2] = a.z; h1[16+4*q+3] = a.w;
        }
    }

    float lin1 = linbase + fc[ids1.x] + fc[ids1.y];
    unsigned mw1[9];
    #pragma unroll
    for (int q = 0; q < 9; ++q) {
        lin1 += mh1[q].x ? fc[kOffset + 2 * q]     : 0.f;
        lin1 += mh1[q].y ? fc[kOffset + 2 * q + 1] : 0.f;
        mw1[q] = (mh1[q].x ? 0x3F80u : 0u) | (mh1[q].y ? 0x3F800000u : 0u);
    }

    // ================= compute (tile 1 loads in flight during tile 0) ==============
    tile_compute(aw, s_w, lane, c, g, mw0, h0, lin0, b1v, b2v, b3v, W4, out, i0);
    tile_compute(aw, s_w, lane, c, g, mw1, h1, lin1, b1v, b2v, b3v, W4, out, i1);
}

} // namespace

extern "C" void kernel_launch(void* const* d_in, const int* in_sizes, int n_in,
                              void* d_out, int out_size, void* d_ws, size_t ws_size,
                              hipStream_t stream) {
    (void)in_sizes; (void)n_in; (void)ws_size; (void)out_size;
    const int*   x_onehot  = (const int*)  d_in[0];
    const int*   multi_hot = (const int*)  d_in[1];
    const float* emb       = (const float*)d_in[2];
    const float* fc        = (const float*)d_in[3];
    const float* W1        = (const float*)d_in[4];
    const float* b1        = (const float*)d_in[5];
    const float* W2        = (const float*)d_in[6];
    const float* b2        = (const float*)d_in[7];
    const float* W3        = (const float*)d_in[8];
    const float* b3        = (const float*)d_in[9];
    const float* W4        = (const float*)d_in[10];
    const float* b4        = (const float*)d_in[11];
    const float* biasp     = (const float*)d_in[12];
    float* out = (float*)d_out;
    unsigned short* wimg = (unsigned short*)d_ws;

    hipLaunchKernelGGL(prep_weights, dim3(1), dim3(256), 0, stream,
                       emb, W1, W2, W3, wimg);
    hipLaunchKernelGGL(deepfm_fwd, dim3(kBatch / 512), dim3(256), 0, stream,
                       x_onehot, multi_hot, emb, fc, wimg,
                       b1, b2, b3, W4, b4, biasp, out);
}

// Round 8
// 39.733 us; speedup vs baseline: 2.5329x; 2.5329x over previous
//
#include <hip/hip_runtime.h>
#include <hip/hip_bf16.h>

namespace {

constexpr int kBatch  = 524288;
constexpr int kD      = 16;
constexpr int kOffset = 38167;   // TOTAL - N_GENRES
constexpr int kNG     = 18;

// s_w byte-offset layout (identical image in d_ws and LDS; swizzle pre-baked).
constexpr int W1B0   = 0;        // W1^T swz [64][64] bf16 (k 0..47 valid, 48..63 zero)
constexpr int W2B0   = 8192;     // W2^T swz [32][64]
constexpr int W3B0   = 12288;    // W3^T swz [16][32]
constexpr int GB0    = 13312;    // genre B-frag table [64 rows=(4c+g)][8] bf16
constexpr int WBYTES = 14336;    // = 896 uint4

typedef __attribute__((ext_vector_type(8))) short short8;   // MFMA A/B frag
typedef __attribute__((ext_vector_type(4))) float f32x4;    // MFMA C/D frag

__device__ __forceinline__ unsigned short f2bf(float f) {
    return __builtin_bit_cast(unsigned short, __float2bfloat16(f));
}
__device__ __forceinline__ unsigned pk2(float a, float b) {
    return (unsigned)f2bf(a) | ((unsigned)f2bf(b) << 16);
}
__device__ __forceinline__ float bf2f(unsigned short s) {
    union { unsigned u; float f; } v; v.u = ((unsigned)s) << 16;
    return v.f;
}

// ---------------- prep: build swizzled bf16 weight image in d_ws (verified r6) ----------------
__global__ void prep_weights(const float* __restrict__ emb,
                             const float* __restrict__ W1,
                             const float* __restrict__ W2,
                             const float* __restrict__ W3,
                             unsigned short* __restrict__ wimg)
{
    const int t = (int)threadIdx.x;             // 256 threads, 1 block
    for (int i = t; i < WBYTES / 2; i += 256) wimg[i] = 0;
    __syncthreads();
    for (int i = t; i < 48 * 64; i += 256) {    // W1^T, swizzled rows
        int k = i >> 6, n = i & 63;
        int byte = W1B0 + n * 128 + ((k * 2) ^ ((n & 7) << 4));
        wimg[byte >> 1] = f2bf(W1[k * 64 + n]);
    }
    for (int i = t; i < 64 * 32; i += 256) {    // W2^T
        int k = i >> 5, n = i & 31;
        int byte = W2B0 + n * 128 + ((k * 2) ^ ((n & 7) << 4));
        wimg[byte >> 1] = f2bf(W2[k * 32 + n]);
    }
    for (int i = t; i < 32 * 16; i += 256) {    // W3^T (64B rows, XOR with n&3)
        int k = i >> 4, n = i & 15;
        int byte = W3B0 + n * 64 + ((k * 2) ^ ((n & 3) << 4));
        wimg[byte >> 1] = f2bf(W3[k * 16 + n]);
    }
    for (int i = t; i < 512; i += 256) {        // genre B-frag: row 4c+g holds G[8g+j][c]
        int c = i >> 5, r = i & 31, g = r >> 3, j = r & 7;
        int kg = 8 * g + j;
        wimg[(GB0 >> 1) + (4 * c + g) * 8 + j] =
            (kg < kNG) ? f2bf(emb[(size_t)(kOffset + kg) * kD + c]) : (unsigned short)0;
    }
}

// ---------------- main fused kernel: 256 thr, 3 blocks/CU, table-addressed LDS ----------------
__global__ __launch_bounds__(256, 3) void deepfm_fwd(
    const int*   __restrict__ x_onehot,
    const int*   __restrict__ multi_hot,
    const float* __restrict__ emb,
    const float* __restrict__ fc,
    const unsigned short* __restrict__ wimg,
    const float* __restrict__ b1,
    const float* __restrict__ b2,
    const float* __restrict__ b3,
    const float* __restrict__ W4,
    const float* __restrict__ b4,
    const float* __restrict__ bias,
    float*       __restrict__ out)
{
    __shared__ alignas(16) unsigned short s_w[WBYTES / 2];  // 14336 B
    __shared__ alignas(16) unsigned short s_act[4 * 4096];  // 32768 B; total 47104 B

    const int t = (int)threadIdx.x;

    // ---- stage weight image global->LDS ----
    {
        const uint4* src = reinterpret_cast<const uint4*>(wimg);
        uint4*       dst = reinterpret_cast<uint4*>(s_w);
        #pragma unroll
        for (int q = 0; q < 4; ++q) {
            const int idx = t + 256 * q;
            if (idx < WBYTES / 16) dst[idx] = src[idx];
        }
    }

    const int i    = (int)blockIdx.x * 256 + t;
    const int lane = t & 63;
    const int w    = t >> 6;
    const int c    = lane & 15, g = lane >> 4;
    char* __restrict__ awc = (char*)(s_act + w * 4096);
    const char* __restrict__ swc = (const char*)s_w;

    // ===== precomputed per-lane LDS byte-offset tables (swizzle folded in) =====
    // storage swizzle: byte_in_row ^= ((row&7)<<4), 128B rows
    const int l7 = lane & 7;
    const int sb = lane * 128;                       // own-row base (rows = lane)
    // A/B fragment reads: row=16*mt+c (or 16*nt+c), col byte 64*kt+16*g
    int rA[2];
    #pragma unroll
    for (int kt = 0; kt < 2; ++kt)
        rA[kt] = c * 128 + (((4 * kt + g) ^ (c & 7)) << 4);
    // epilogue writes: row=16*mt+4*g+r, col=16*nt+c  ->  wad[r][nt] + 2048*mt
    int wad[4][4];
    #pragma unroll
    for (int r = 0; r < 4; ++r) {
        const int Xlo  = (r & 1) << 4;
        const int Xhi  = (2 * (g & 1) + (r >> 1)) << 5;
        const int rowb = (4 * g + r) * 128 + ((2 * c) ^ Xlo);
        #pragma unroll
        for (int nt = 0; nt < 4; ++nt)
            wad[r][nt] = rowb + ((32 * nt) ^ Xhi);
    }
    const int rW3 = W3B0 + c * 64 + ((g ^ (c & 3)) << 4);

    // ---- independent global loads issued early ----
    int2 mh[9];
    {
        const int2* mh2 = reinterpret_cast<const int2*>(multi_hot + (size_t)kNG * i);
        #pragma unroll
        for (int q = 0; q < 9; ++q) mh[q] = mh2[q];
    }
    const int2 ids = *reinterpret_cast<const int2*>(x_onehot + 2 * (size_t)i);

    float h[32];
    {
        const float4* eu = reinterpret_cast<const float4*>(emb + (size_t)ids.x * kD);
        #pragma unroll
        for (int q = 0; q < 4; ++q) {
            const float4 a = eu[q];
            h[4*q+0] = a.x; h[4*q+1] = a.y; h[4*q+2] = a.z; h[4*q+3] = a.w;
        }
        const float4* ei = reinterpret_cast<const float4*>(emb + (size_t)ids.y * kD);
        #pragma unroll
        for (int q = 0; q < 4; ++q) {
            const float4 a = ei[q];
            h[16+4*q+0] = a.x; h[16+4*q+1] = a.y; h[16+4*q+2] = a.z; h[16+4*q+3] = a.w;
        }
    }

    // per-lane column biases
    float b1v[4];
    #pragma unroll
    for (int nt = 0; nt < 4; ++nt) b1v[nt] = b1[16 * nt + c];
    float b2v[2]; b2v[0] = b2[c]; b2v[1] = b2[16 + c];
    const float b3v = b3[c];

    // ---- first-order term ----
    float lin = bias[0] + b4[0] + fc[ids.x] + fc[ids.y];
    #pragma unroll
    for (int q = 0; q < 9; ++q) {
        lin += mh[q].x ? fc[kOffset + 2 * q]     : 0.f;
        lin += mh[q].y ? fc[kOffset + 2 * q + 1] : 0.f;
    }

    // ---- stage m-row (bf16 0/1) cols 0..31 (granules 0..3); zeros granules 6,7 ----
    {
        unsigned mw[9];
        #pragma unroll
        for (int q = 0; q < 9; ++q)
            mw[q] = (mh[q].x ? 0x3F80u : 0u) | (mh[q].y ? 0x3F800000u : 0u);
        uint4 v0; v0.x = mw[0]; v0.y = mw[1]; v0.z = mw[2]; v0.w = mw[3];
        uint4 v1; v1.x = mw[4]; v1.y = mw[5]; v1.z = mw[6]; v1.w = mw[7];
        uint4 v2; v2.x = mw[8]; v2.y = 0u;    v2.z = 0u;    v2.w = 0u;
        uint4 vz; vz.x = vz.y = vz.z = vz.w = 0u;
        *reinterpret_cast<uint4*>(awc + sb + (((0 ^ l7)) << 4)) = v0;
        *reinterpret_cast<uint4*>(awc + sb + (((1 ^ l7)) << 4)) = v1;
        *reinterpret_cast<uint4*>(awc + sb + (((2 ^ l7)) << 4)) = v2;
        *reinterpret_cast<uint4*>(awc + sb + (((3 ^ l7)) << 4)) = vz;
        *reinterpret_cast<uint4*>(awc + sb + (((6 ^ l7)) << 4)) = vz;
        *reinterpret_cast<uint4*>(awc + sb + (((7 ^ l7)) << 4)) = vz;
    }

    __syncthreads();   // weight image ready

    const f32x4 z4 = {0.f, 0.f, 0.f, 0.f};

    // ---- embedding-bag via MFMA: e_mh = m @ G  -> act cols 32..47 ----
    {
        const short8 bfrag = *reinterpret_cast<const short8*>(s_w + (GB0 >> 1) + (4 * c + g) * 8);
        short8 af[4];
        #pragma unroll
        for (int mt = 0; mt < 4; ++mt)
            af[mt] = *reinterpret_cast<const short8*>(awc + rA[0] + 2048 * mt);
        f32x4 accb[4];
        #pragma unroll
        for (int mt = 0; mt < 4; ++mt)
            accb[mt] = __builtin_amdgcn_mfma_f32_16x16x32_bf16(af[mt], bfrag, z4, 0, 0, 0);
        #pragma unroll
        for (int mt = 0; mt < 4; ++mt)
            #pragma unroll
            for (int r = 0; r < 4; ++r)
                *reinterpret_cast<unsigned short*>(awc + wad[r][2] + 2048 * mt) = f2bf(accb[mt][r]);
    }

    // ---- pack e_user|e_item -> act cols 0..31 (after bag A-reads; same-wave DS order) ----
    {
        #pragma unroll
        for (int q = 0; q < 4; ++q) {
            uint4 d;
            d.x = pk2(h[8*q+0], h[8*q+1]);
            d.y = pk2(h[8*q+2], h[8*q+3]);
            d.z = pk2(h[8*q+4], h[8*q+5]);
            d.w = pk2(h[8*q+6], h[8*q+7]);
            *reinterpret_cast<uint4*>(awc + sb + ((q ^ l7) << 4)) = d;
        }
    }

    // ---- read back e_mh for FM (granules 4,5 of own row) ----
    float fm = 0.f;
    {
        const uint4 p0 = *reinterpret_cast<const uint4*>(awc + sb + ((4 ^ l7) << 4));
        const uint4 p1 = *reinterpret_cast<const uint4*>(awc + sb + ((5 ^ l7) << 4));
        const unsigned pp[8] = {p0.x, p0.y, p0.z, p0.w, p1.x, p1.y, p1.z, p1.w};
        float em[16];
        #pragma unroll
        for (int j = 0; j < 8; ++j) {
            em[2*j+0] = bf2f((unsigned short)(pp[j] & 0xFFFFu));
            em[2*j+1] = bf2f((unsigned short)(pp[j] >> 16));
        }
        #pragma unroll
        for (int d = 0; d < kD; ++d) fm = fmaf(h[d], h[16 + d], fm);
        #pragma unroll
        for (int d = 0; d < kD; ++d) fm = fmaf(h[d] + h[16 + d], em[d], fm);
    }

    // ================= L1: act[64x64] @ W1 (K=48 padded to 64) =================
    f32x4 acc1[4][4];
    #pragma unroll
    for (int mt = 0; mt < 4; ++mt)
        #pragma unroll
        for (int nt = 0; nt < 4; ++nt) acc1[mt][nt] = z4;
    #pragma unroll
    for (int kt = 0; kt < 2; ++kt) {
        short8 af[4], bfr[4];
        #pragma unroll
        for (int mt = 0; mt < 4; ++mt)
            af[mt] = *reinterpret_cast<const short8*>(awc + rA[kt] + 2048 * mt);
        #pragma unroll
        for (int nt = 0; nt < 4; ++nt)
            bfr[nt] = *reinterpret_cast<const short8*>(swc + W1B0 + rA[kt] + 2048 * nt);
        #pragma unroll
        for (int mt = 0; mt < 4; ++mt)
            #pragma unroll
            for (int nt = 0; nt < 4; ++nt)
                acc1[mt][nt] = __builtin_amdgcn_mfma_f32_16x16x32_bf16(af[mt], bfr[nt], acc1[mt][nt], 0, 0, 0);
    }
    #pragma unroll
    for (int mt = 0; mt < 4; ++mt)
        #pragma unroll
        for (int nt = 0; nt < 4; ++nt)
            #pragma unroll
            for (int r = 0; r < 4; ++r) {
                const float v = fmaxf(acc1[mt][nt][r] + b1v[nt], 0.f);
                *reinterpret_cast<unsigned short*>(awc + wad[r][nt] + 2048 * mt) = f2bf(v);
            }

    // ================= L2: h1[64x64] @ W2[64x32] =================
    f32x4 acc2[4][2];
    #pragma unroll
    for (int mt = 0; mt < 4; ++mt)
        #pragma unroll
        for (int nt = 0; nt < 2; ++nt) acc2[mt][nt] = z4;
    #pragma unroll
    for (int kt = 0; kt < 2; ++kt) {
        short8 af[4], bfr[2];
        #pragma unroll
        for (int mt = 0; mt < 4; ++mt)
            af[mt] = *reinterpret_cast<const short8*>(awc + rA[kt] + 2048 * mt);
        #pragma unroll
        for (int nt = 0; nt < 2; ++nt)
            bfr[nt] = *reinterpret_cast<const short8*>(swc + W2B0 + rA[kt] + 2048 * nt);
        #pragma unroll
        for (int mt = 0; mt < 4; ++mt)
            #pragma unroll
            for (int nt = 0; nt < 2; ++nt)
                acc2[mt][nt] = __builtin_amdgcn_mfma_f32_16x16x32_bf16(af[mt], bfr[nt], acc2[mt][nt], 0, 0, 0);
    }
    #pragma unroll
    for (int mt = 0; mt < 4; ++mt)
        #pragma unroll
        for (int nt = 0; nt < 2; ++nt)
            #pragma unroll
            for (int r = 0; r < 4; ++r) {
                const float v = fmaxf(acc2[mt][nt][r] + b2v[nt], 0.f);
                *reinterpret_cast<unsigned short*>(awc + wad[r][nt] + 2048 * mt) = f2bf(v);
            }

    // ================= L3: h2[64x32] @ W3[32x16] =================
    f32x4 acc3[4];
    #pragma unroll
    for (int mt = 0; mt < 4; ++mt) acc3[mt] = z4;
    {
        const short8 bfr = *reinterpret_cast<const short8*>(swc + rW3);
        short8 af[4];
        #pragma unroll
        for (int mt = 0; mt < 4; ++mt)
            af[mt] = *reinterpret_cast<const short8*>(awc + rA[0] + 2048 * mt);
        #pragma unroll
        for (int mt = 0; mt < 4; ++mt)
            acc3[mt] = __builtin_amdgcn_mfma_f32_16x16x32_bf16(af[mt], bfr, acc3[mt], 0, 0, 0);
    }
    #pragma unroll
    for (int mt = 0; mt < 4; ++mt)
        #pragma unroll
        for (int r = 0; r < 4; ++r) {
            const float v = fmaxf(acc3[mt][r] + b3v, 0.f);
            *reinterpret_cast<unsigned short*>(awc + wad[r][0] + 2048 * mt) = f2bf(v);
        }

    // ================= L4 (16 -> 1) + combine + sigmoid =================
    float mlp = 0.f;
    {
        const uint4 p0 = *reinterpret_cast<const uint4*>(awc + sb + ((0 ^ l7) << 4));
        const uint4 p1 = *reinterpret_cast<const uint4*>(awc + sb + ((1 ^ l7) << 4));
        const unsigned pp[8] = {p0.x, p0.y, p0.z, p0.w, p1.x, p1.y, p1.z, p1.w};
        #pragma unroll
        for (int j = 0; j < 8; ++j) {
            mlp = fmaf(bf2f((unsigned short)(pp[j] & 0xFFFFu)), W4[2*j],     mlp);
            mlp = fmaf(bf2f((unsigned short)(pp[j] >> 16)),     W4[2*j + 1], mlp);
        }
    }

    const float x = lin + fm + mlp;
    out[i] = 1.0f / (1.0f + __expf(-x));
}

} // namespace

extern "C" void kernel_launch(void* const* d_in, const int* in_sizes, int n_in,
                              void* d_out, int out_size, void* d_ws, size_t ws_size,
                              hipStream_t stream) {
    (void)in_sizes; (void)n_in; (void)ws_size; (void)out_size;
    const int*   x_onehot  = (const int*)  d_in[0];
    const int*   multi_hot = (const int*)  d_in[1];
    const float* emb       = (const float*)d_in[2];
    const float* fc        = (const float*)d_in[3];
    const float* W1        = (const float*)d_in[4];
    const float* b1        = (const float*)d_in[5];
    const float* W2        = (const float*)d_in[6];
    const float* b2        = (const float*)d_in[7];
    const float* W3        = (const float*)d_in[8];
    const float* b3        = (const float*)d_in[9];
    const float* W4        = (const float*)d_in[10];
    const float* b4        = (const float*)d_in[11];
    const float* biasp     = (const float*)d_in[12];
    float* out = (float*)d_out;
    unsigned short* wimg = (unsigned short*)d_ws;

    hipLaunchKernelGGL(prep_weights, dim3(1), dim3(256), 0, stream,
                       emb, W1, W2, W3, wimg);
    hipLaunchKernelGGL(deepfm_fwd, dim3(kBatch / 256), dim3(256), 0, stream,
                       x_onehot, multi_hot, emb, fc, wimg,
                       b1, b2, b3, W4, b4, biasp, out);
}